// Round 3
// baseline (115.478 us; speedup 1.0000x reference)
//
#include <hip/hip_runtime.h>

// CPCircuitLayer, v3: algebraic refactor.
//   out[row,h] = sum_r (sum_h' hs[row,h']*W[r,h']) * he[h,r]*cp[r]
//             = sum_h' hs[row,h'] * K[h',h],   K[h',h] = sum_r W[r,h']*he[h,r]*cp[r]
// all_indices is the identity enumeration -- never read.
//
// v2 post-mortem: 256-thread blocks = 4 waves, 1 block/CU -> 1 wave/SIMD; 16
// barrier-vmcnt(0) drains with nothing to overlap -> 99.9% stall (VALUBusy
// 0.11%). v3: two barrier-light kernels, every global access coalesced, 8
// waves/CU in the main GEMM. K (1 MB) lives in d_ws and stays L2-hot.

#define Hd 512
#define Rd 64

// ---------- kernel P: K[h'][h] = sum_r W[r][h']*cp[r] * he[h][r] ----------
// 64 blocks x 256 thr; block b owns h' in [8b, 8b+8).
__global__ __launch_bounds__(256) void cp_precompute_K(
    const float* __restrict__ W,    // (64, 512)
    const float* __restrict__ he,   // (512, 64)
    const float* __restrict__ cp,   // (64)
    float* __restrict__ K)          // (512, 512)
{
    __shared__ float s_W[8][Rd];        // [i][r] = W[r][h'0+i]*cp[r]
    __shared__ float s_he[128 * 65];    // [hl][r], pad 65: (hl+r)%32 -> 2-way = free

    const int t = threadIdx.x;
    const int hp0 = blockIdx.x * 8;

    {   // stage W columns (tiny, semi-coalesced is fine)
        const int i = t & 7, r = t >> 3;               // r in 0..31
        s_W[i][r]      = W[r * Hd + hp0 + i] * cp[r];
        s_W[i][r + 32] = W[(r + 32) * Hd + hp0 + i] * cp[r + 32];
    }

    const int hl = t & 127;             // h within 128-chunk
    const int ig = (t >> 7) * 4;        // h' sub-group 0 or 4 (wave-uniform)

    for (int hc = 0; hc < 4; ++hc) {
        __syncthreads();                // prev-iter reads done (also fences s_W stage)
        // stage he chunk: contiguous 32 KB slab, fully coalesced
        const float4* src = (const float4*)(he + (size_t)hc * 128 * Rd);
#pragma unroll
        for (int k = 0; k < 8; ++k) {
            const int f = t + k * 256;                 // float4 index 0..2047
            const int h = f >> 4, r4 = f & 15;
            const float4 v = src[f];
            float* d = &s_he[h * 65 + 4 * r4];
            d[0] = v.x; d[1] = v.y; d[2] = v.z; d[3] = v.w;
        }
        __syncthreads();

        float a0 = 0.f, a1 = 0.f, a2 = 0.f, a3 = 0.f;
        const float* hrow = &s_he[hl * 65];
#pragma unroll
        for (int r = 0; r < Rd; ++r) {
            const float hv = hrow[r];                  // 2-way bank alias: free
            a0 += hv * s_W[ig + 0][r];                 // wave-broadcast
            a1 += hv * s_W[ig + 1][r];
            a2 += hv * s_W[ig + 2][r];
            a3 += hv * s_W[ig + 3][r];
        }
        const int h = hc * 128 + hl;
        K[(hp0 + ig + 0) * Hd + h] = a0;               // coalesced
        K[(hp0 + ig + 1) * Hd + h] = a1;
        K[(hp0 + ig + 2) * Hd + h] = a2;
        K[(hp0 + ig + 3) * Hd + h] = a3;
    }
}

// ---------- kernel G: out = hs (2048x512) . K (512x512) ----------
// 256 blocks x 512 thr (8 waves/CU). Block owns 8 rows. Thread: hcol=t&255
// (output cols 2*hcol, 2*hcol+1), half=t>>8 splits the K-dimension h' in two;
// one LDS reduction at the end. K loads: 64 lanes x float2 = 512 B contiguous.
__global__ __launch_bounds__(512) void cp_gemm(
    const float* __restrict__ hs,   // (2048, 512)
    const float* __restrict__ K,    // (512, 512)
    float* __restrict__ out)        // (2048, 512)
{
    __shared__ float s_hs[8][Hd];           // 16 KB
    __shared__ float2 s_red[256][9];        // 18 KB, pad 9: 2-way alias = free

    const int t = threadIdx.x;
    const size_t row0 = (size_t)blockIdx.x * 8;

    {   // stage 8 hs rows: 1024 float4, coalesced
        const float4* src = (const float4*)(hs + row0 * Hd);
        float4* dst = (float4*)&s_hs[0][0];
        dst[t] = src[t];
        dst[t + 512] = src[t + 512];
    }
    __syncthreads();

    const int hcol = t & 255;
    const int half = t >> 8;                // wave-uniform
    const int hpB = half * 256;             // this half's h' range

    float2 acc[8];
#pragma unroll
    for (int i = 0; i < 8; ++i) acc[i] = make_float2(0.f, 0.f);

    const float2* K2 = (const float2*)K;    // K2[h'*256 + hcol]

    for (int hp = 0; hp < 256; hp += 4) {
        float2 kv0 = K2[(hpB + hp + 0) * 256 + hcol];   // 4 independent L2 streams
        float2 kv1 = K2[(hpB + hp + 1) * 256 + hcol];
        float2 kv2 = K2[(hpB + hp + 2) * 256 + hcol];
        float2 kv3 = K2[(hpB + hp + 3) * 256 + hcol];
#pragma unroll
        for (int i = 0; i < 8; ++i) {
            const float4 a = *(const float4*)&s_hs[i][hpB + hp];  // b128 broadcast
            acc[i].x += a.x * kv0.x + a.y * kv1.x + a.z * kv2.x + a.w * kv3.x;
            acc[i].y += a.x * kv0.y + a.y * kv1.y + a.z * kv2.y + a.w * kv3.y;
        }
    }

    // reduce the two h'-halves
    if (half == 1) {
#pragma unroll
        for (int i = 0; i < 8; ++i) s_red[hcol][i] = acc[i];
    }
    __syncthreads();
    if (half == 0) {
#pragma unroll
        for (int i = 0; i < 8; ++i) {
            const float2 p = s_red[hcol][i];
            acc[i].x += p.x;
            acc[i].y += p.y;
            *(float2*)&out[(row0 + i) * Hd + 2 * hcol] = acc[i];  // 512 B/wave
        }
    }
}

extern "C" void kernel_launch(void* const* d_in, const int* in_sizes, int n_in,
                              void* d_out, int out_size, void* d_ws, size_t ws_size,
                              hipStream_t stream) {
    const float* hs = (const float*)d_in[0];  // hidden_states (2,1024,512) f32
    // d_in[1] = all_indices -- identity mapping, unused
    const float* W  = (const float*)d_in[2];  // W_seq (64,512) f32
    const float* he = (const float*)d_in[3];  // hidden_embeddings (512,64) f32
    const float* cp = (const float*)d_in[4];  // cp_weight (1,64) f32
    float* out = (float*)d_out;               // (2,1024,512) f32
    float* Kbuf = (float*)d_ws;               // 512x512 f32 = 1 MB scratch

    cp_precompute_K<<<dim3(64), dim3(256), 0, stream>>>(W, he, cp, Kbuf);
    cp_gemm<<<dim3(256), dim3(512), 0, stream>>>(hs, Kbuf, out);
}

// Round 4
// 89.583 us; speedup vs baseline: 1.2891x; 1.2891x over previous
//
#include <hip/hip_runtime.h>

// CPCircuitLayer, v4: bf16 MFMA, zero barriers.
//   out[row,h] = sum_h' hs[row,h'] * KT[h][h'],  KT[h][h'] = sum_r he[h,r]*cp[r]*W[r,h']
// all_indices is the identity enumeration -- never read.
//
// v3 post-mortem: fp32 VALU GEMM stalled at 21% VALUBusy (dependent L2 loads,
// 2 waves/SIMD); K-precompute itself cost ~35 us (barrier-chained, 64 blocks).
// v4: (1) KT precompute as a plain streaming kernel, 256 blocks, coalesced W
// reads, bf16 output (512 KB in d_ws). (2) GEMM via mfma_f32_16x16x32_bf16
// with NO LDS and NO barriers: A-frag = 2 float4 from fp32 hs + inline cvt
// (A[m=lane&15][k=quad*8+j]); B-frag = one 16B load from KT, whose row-major
// [n][k] layout is exactly the B-operand layout. 1024 blocks x 256 thr =
// 4 blocks/CU = 4 waves/SIMD; latency hidden by TLP + unroll, not barriers.

typedef __bf16 bf16x8 __attribute__((ext_vector_type(8)));
typedef float f32x4 __attribute__((ext_vector_type(4)));

// ---------- kernel P: KT[h][h'] = sum_r he[h][r]*cp[r] * W[r][h'] ----------
// 256 blocks x 256 thr; block b owns h rows {2b, 2b+1}; thread t owns cols
// {t, t+256}. W reads are lane-consecutive (coalesced); 128 loads/thread,
// unrolled 8 deep for MLP.
__global__ __launch_bounds__(256) void cp_K(
    const float* __restrict__ W,    // (64, 512)
    const float* __restrict__ he,   // (512, 64)
    const float* __restrict__ cp,   // (64)
    __bf16* __restrict__ KT)        // (512, 512) [h][h']
{
    __shared__ float s_he[2][64];
    const int t = threadIdx.x;
    const int h0 = blockIdx.x * 2;
    if (t < 128) {
        const int hh = t >> 6, r = t & 63;
        s_he[hh][r] = he[(h0 + hh) * 64 + r] * cp[r];
    }
    __syncthreads();

    float a00 = 0.f, a01 = 0.f, a10 = 0.f, a11 = 0.f;
#pragma unroll 8
    for (int r = 0; r < 64; ++r) {
        const float w0 = W[r * 512 + t];         // coalesced
        const float w1 = W[r * 512 + t + 256];   // coalesced
        const float e0 = s_he[0][r];             // broadcast
        const float e1 = s_he[1][r];
        a00 += e0 * w0; a01 += e0 * w1;
        a10 += e1 * w0; a11 += e1 * w1;
    }
    KT[(size_t)h0 * 512 + t]             = (__bf16)a00;
    KT[(size_t)h0 * 512 + t + 256]       = (__bf16)a01;
    KT[(size_t)(h0 + 1) * 512 + t]       = (__bf16)a10;
    KT[(size_t)(h0 + 1) * 512 + t + 256] = (__bf16)a11;
}

// ---------- kernel G: out (2048x512) = hs (2048x512) . KT^T ----------
// Tile 32x32 per block (4 waves, each one 16x16 mfma tile). 1024 blocks.
// XCD swizzle: the 16 n-tiles sharing one m-tile's A-rows land on one XCD.
__global__ __launch_bounds__(256) void cp_gemm_mfma(
    const float* __restrict__ hs,   // (2048, 512) f32
    const __bf16* __restrict__ KT,  // (512, 512) bf16, [n][k]
    float* __restrict__ out)        // (2048, 512) f32
{
    const int t = threadIdx.x;
    const int w = t >> 6;
    const int L = t & 63;
    const int mq = L & 15;          // frag m (A) / n (B) / col (D)
    const int kq = L >> 4;          // k-quad

    // bx -> (mt, nt) with XCD grouping: xcd = bx&7 (hw round-robin), so give
    // each xcd a contiguous run of 8 mt values (16 nt-blocks per mt).
    const int bx = blockIdx.x;
    const int idx = (bx & 7) * 128 + (bx >> 3);
    const int mt = idx >> 4, nt = idx & 15;

    const int m0 = mt * 32 + (w >> 1) * 16;
    const int n0 = nt * 32 + (w & 1) * 16;

    const float*  aRow = hs + (size_t)(m0 + mq) * 512 + kq * 8;
    const __bf16* bRow = KT + (size_t)(n0 + mq) * 512 + kq * 8;

    f32x4 acc = {0.f, 0.f, 0.f, 0.f};
#pragma unroll 4
    for (int ks = 0; ks < 16; ++ks) {
        const float4 f0 = *(const float4*)(aRow + ks * 32);
        const float4 f1 = *(const float4*)(aRow + ks * 32 + 4);
        const bf16x8 b  = *(const bf16x8*)(bRow + ks * 32);
        bf16x8 a;
        a[0] = (__bf16)f0.x; a[1] = (__bf16)f0.y; a[2] = (__bf16)f0.z; a[3] = (__bf16)f0.w;
        a[4] = (__bf16)f1.x; a[5] = (__bf16)f1.y; a[6] = (__bf16)f1.z; a[7] = (__bf16)f1.w;
        acc = __builtin_amdgcn_mfma_f32_16x16x32_bf16(a, b, acc, 0, 0, 0);
    }

    // D layout: col = lane&15 -> n0+mq; row = (lane>>4)*4 + reg -> m0+kq*4+i
    float* op = out + (size_t)(m0 + kq * 4) * 512 + n0 + mq;
    op[0]        = acc[0];
    op[512]      = acc[1];
    op[2 * 512]  = acc[2];
    op[3 * 512]  = acc[3];
}

extern "C" void kernel_launch(void* const* d_in, const int* in_sizes, int n_in,
                              void* d_out, int out_size, void* d_ws, size_t ws_size,
                              hipStream_t stream) {
    const float* hs = (const float*)d_in[0];  // hidden_states (2,1024,512) f32
    // d_in[1] = all_indices -- identity mapping, unused
    const float* W  = (const float*)d_in[2];  // W_seq (64,512) f32
    const float* he = (const float*)d_in[3];  // hidden_embeddings (512,64) f32
    const float* cp = (const float*)d_in[4];  // cp_weight (1,64) f32
    float* out = (float*)d_out;               // (2,1024,512) f32
    __bf16* KT = (__bf16*)d_ws;               // 512x512 bf16 = 512 KB scratch

    cp_K<<<dim3(256), dim3(256), 0, stream>>>(W, he, cp, KT);
    cp_gemm_mfma<<<dim3(1024), dim3(256), 0, stream>>>(hs, KT, out);
}

// Round 6
// 80.645 us; speedup vs baseline: 1.4319x; 1.1108x over previous
//
#include <hip/hip_runtime.h>

// CPCircuitLayer, v6: all-bf16 MFMA GEMM + fused prep (v5 with cvt OOB fixed).
//   out[row,h] = sum_h' hs[row,h'] * KT[h][h'],  KT[h][h'] = sum_r he[h,r]*cp[r]*W[r,h']
// all_indices is the identity enumeration -- never read.
//
// v5 post-mortem: core dump was an OOB in the cvt half of cp_prep -- hs is
// 262,144 float4 (1024/block), v5 indexed b*4096 + i<16 (4x over-count,
// 12 MB OOB read). Fixed: b*1024, i<4. Design unchanged: (1) prep kernel,
// 384 independent blocks (256 cvt hs->bf16 streaming, 128 build KT in bf16);
// (2) GEMM via mfma_f32_16x16x32_bf16, 64m x 32n tile/block, A-frag reused
// across 2 B-frags, zero LDS, zero barriers, 512 blocks.

typedef __bf16 bf16x4 __attribute__((ext_vector_type(4)));
typedef __bf16 bf16x8 __attribute__((ext_vector_type(8)));
typedef float f32x4 __attribute__((ext_vector_type(4)));

// ---------- kernel 1: prep ----------
// blocks 0..255: hsb = (bf16)hs, 4096 floats/block (1024 float4), streaming.
// blocks 256..383: KT rows [4 per block]: KT[h][h'] = sum_r he[h][r]*cp[r]*W[r][h'].
__global__ __launch_bounds__(256) void cp_prep(
    const float* __restrict__ hs,   // (2048, 512)
    const float* __restrict__ W,    // (64, 512)
    const float* __restrict__ he,   // (512, 64)
    const float* __restrict__ cp,   // (64)
    __bf16* __restrict__ hsb,       // (2048, 512) bf16
    __bf16* __restrict__ KT)        // (512, 512) bf16, [h][h']
{
    const int t = threadIdx.x;
    const int b = blockIdx.x;

    if (b < 256) {
        const float4* src = (const float4*)hs + (size_t)b * 1024;
        bf16x4* dst = (bf16x4*)hsb + (size_t)b * 1024;
#pragma unroll
        for (int i = 0; i < 4; ++i) {
            const float4 v = src[t + i * 256];
            bf16x4 o;
            o[0] = (__bf16)v.x; o[1] = (__bf16)v.y;
            o[2] = (__bf16)v.z; o[3] = (__bf16)v.w;
            dst[t + i * 256] = o;
        }
        return;
    }

    // KT part: 128 blocks, 4 h-rows each
    __shared__ float s_he[4][64];
    const int h0 = (b - 256) * 4;
    if (t < 64) {   // stage he[h0..h0+4][:] * cp, coalesced float4
        const float4 v = ((const float4*)(he + (size_t)h0 * 64))[t];
        const float4 c = ((const float4*)cp)[t & 15];
        float* d = &s_he[t >> 4][4 * (t & 15)];
        d[0] = v.x * c.x; d[1] = v.y * c.y; d[2] = v.z * c.z; d[3] = v.w * c.w;
    }
    __syncthreads();

    float a0[4] = {0.f, 0.f, 0.f, 0.f};
    float a1[4] = {0.f, 0.f, 0.f, 0.f};
#pragma unroll 8
    for (int r = 0; r < 64; ++r) {
        const float w0 = W[r * 512 + t];          // coalesced
        const float w1 = W[r * 512 + t + 256];    // coalesced
#pragma unroll
        for (int h = 0; h < 4; ++h) {
            const float e = s_he[h][r];           // broadcast
            a0[h] += e * w0;
            a1[h] += e * w1;
        }
    }
#pragma unroll
    for (int h = 0; h < 4; ++h) {                 // coalesced bf16 stores
        KT[(size_t)(h0 + h) * 512 + t]       = (__bf16)a0[h];
        KT[(size_t)(h0 + h) * 512 + t + 256] = (__bf16)a1[h];
    }
}

// ---------- kernel 2: out (2048x512) = hsb . KT^T ----------
// 512 blocks x 256 thr, tile 64m x 32n; wave w owns rows [m0+16w, +16) x all
// 32 n (2 B-frags per A-frag -> 3 loads : 2 MFMA). Zero LDS, zero barriers.
__global__ __launch_bounds__(256) void cp_gemm_mfma(
    const __bf16* __restrict__ A,   // hsb (2048, 512)
    const __bf16* __restrict__ KT,  // (512, 512) [n][k]
    float* __restrict__ out)        // (2048, 512)
{
    const int t = threadIdx.x;
    const int w = t >> 6;
    const int L = t & 63;
    const int mq = L & 15;          // frag m (A) / n (B) / col (D)
    const int kq = L >> 4;          // k-quad

    // XCD swizzle: hw round-robins bx&7; give each XCD 64 consecutive idx so
    // the 16 blocks sharing an A-slab land together.
    const int bx = blockIdx.x;
    const int idx = (bx & 7) * 64 + (bx >> 3);
    const int mt = idx >> 4, nt = idx & 15;

    const int m0 = mt * 64 + w * 16;
    const int n0 = nt * 32;

    const __bf16* aRow  = A  + (size_t)(m0 + mq) * 512 + kq * 8;
    const __bf16* bRow0 = KT + (size_t)(n0 + mq) * 512 + kq * 8;
    const __bf16* bRow1 = bRow0 + 16 * 512;

    f32x4 acc0 = {0.f, 0.f, 0.f, 0.f};
    f32x4 acc1 = {0.f, 0.f, 0.f, 0.f};
#pragma unroll 4
    for (int ks = 0; ks < 16; ++ks) {
        const bf16x8 a  = *(const bf16x8*)(aRow  + ks * 32);
        const bf16x8 b0 = *(const bf16x8*)(bRow0 + ks * 32);
        const bf16x8 b1 = *(const bf16x8*)(bRow1 + ks * 32);
        acc0 = __builtin_amdgcn_mfma_f32_16x16x32_bf16(a, b0, acc0, 0, 0, 0);
        acc1 = __builtin_amdgcn_mfma_f32_16x16x32_bf16(a, b1, acc1, 0, 0, 0);
    }

    // D layout: col = lane&15 -> n + mq; row = (lane>>4)*4 + reg -> m0+kq*4+i
    float* op0 = out + (size_t)(m0 + kq * 4) * 512 + n0 + mq;
    float* op1 = op0 + 16;
#pragma unroll
    for (int i = 0; i < 4; ++i) {
        op0[i * 512] = acc0[i];
        op1[i * 512] = acc1[i];
    }
}

extern "C" void kernel_launch(void* const* d_in, const int* in_sizes, int n_in,
                              void* d_out, int out_size, void* d_ws, size_t ws_size,
                              hipStream_t stream) {
    const float* hs = (const float*)d_in[0];  // hidden_states (2,1024,512) f32
    // d_in[1] = all_indices -- identity mapping, unused
    const float* W  = (const float*)d_in[2];  // W_seq (64,512) f32
    const float* he = (const float*)d_in[3];  // hidden_embeddings (512,64) f32
    const float* cp = (const float*)d_in[4];  // cp_weight (1,64) f32
    float* out = (float*)d_out;               // (2,1024,512) f32

    __bf16* KT  = (__bf16*)d_ws;                          // 512 KB
    __bf16* hsb = (__bf16*)((char*)d_ws + (512 * 1024));  // 2 MB

    cp_prep<<<dim3(384), dim3(256), 0, stream>>>(hs, W, he, cp, hsb, KT);
    cp_gemm_mfma<<<dim3(512), dim3(256), 0, stream>>>(hsb, KT, out);
}

// Round 7
// 78.460 us; speedup vs baseline: 1.4718x; 1.0278x over previous
//
#include <hip/hip_runtime.h>

// CPCircuitLayer, v7: single fused kernel, zero workspace.
//   out[row,h] = sum_h' hs[row,h'] * KT[h][h'],  KT[h][h'] = sum_r he[h,r]*cp[r]*W[r,h']
// all_indices is the identity enumeration -- never read.
//
// v6 post-mortem: dur_us 80.6; kernels ~5 us vs ~76 us harness floor (268 MB
// ws re-poison at 82% HBM dominates every profile). Remaining controllable:
// 2nd launch + hsb/KT round-trips (6 MB). v7 fuses: each block MFMA-builds its
// own 32 KT rows in LDS (M=32,N=512,K=64; 128 MFMAs, 32x redundant across
// mt-blocks but MFMA-cheap), one barrier, then the v6 main loop with inline
// fp32->bf16 A cvt and B-frags via ds_read_b128 from LDS (row pad 520 elems ->
// 8 lanes per 4-bank group = b128 8-phase floor). One launch, no d_ws.

typedef __bf16 bf16x8 __attribute__((ext_vector_type(8)));
typedef float f32x4 __attribute__((ext_vector_type(4)));

#define KPAD 520   // 32 KT rows x 520 bf16 = 33,280 B LDS; %8==0 keeps b128 align

__global__ __launch_bounds__(256) void cp_fused_v7(
    const float* __restrict__ hs,   // (2048, 512) f32
    const float* __restrict__ W,    // (64, 512)  f32
    const float* __restrict__ he,   // (512, 64)  f32
    const float* __restrict__ cp,   // (64)       f32
    float* __restrict__ out)        // (2048, 512) f32
{
    __shared__ __bf16 KTloc[32 * KPAD];

    const int t = threadIdx.x;
    const int w = t >> 6;           // wave 0..3
    const int L = t & 63;
    const int mq = L & 15;          // frag m (A) / n (B) / col (D)
    const int kq = L >> 4;          // k-quad

    // XCD swizzle: hw round-robins bx&7; 64 consecutive idx per XCD so the 16
    // nt-blocks sharing an mt A-slab land on one XCD.
    const int bx = blockIdx.x;
    const int idx = (bx & 7) * 64 + (bx >> 3);
    const int mt = idx >> 4, nt = idx & 15;   // mt 0..31 (64 rows), nt 0..15 (32 cols)

    const int m0 = mt * 64 + w * 16;
    const int n0 = nt * 32;

    // ---------------- phase A: KTloc[h-n0][h'] = sum_r he[h,r]cp[r] W[r,h'] ----------
    // MFMA GEMM M=32 (h rows n0..n0+32), N=512 (h'), K=64 (r). Wave w owns
    // n'-tiles tnG = 8w..8w+7. A-frags (4: tm x ks) built once.
    {
        bf16x8 af[2][2];
#pragma unroll
        for (int tm = 0; tm < 2; ++tm)
#pragma unroll
            for (int ks = 0; ks < 2; ++ks) {
                const float* hp = he + (size_t)(n0 + tm * 16 + mq) * 64 + ks * 32 + kq * 8;
                const float4 h0 = *(const float4*)hp;
                const float4 h1 = *(const float4*)(hp + 4);
                const float4 c0 = *(const float4*)(cp + ks * 32 + kq * 8);
                const float4 c1 = *(const float4*)(cp + ks * 32 + kq * 8 + 4);
                bf16x8 a;
                a[0] = (__bf16)(h0.x * c0.x); a[1] = (__bf16)(h0.y * c0.y);
                a[2] = (__bf16)(h0.z * c0.z); a[3] = (__bf16)(h0.w * c0.w);
                a[4] = (__bf16)(h1.x * c1.x); a[5] = (__bf16)(h1.y * c1.y);
                a[6] = (__bf16)(h1.z * c1.z); a[7] = (__bf16)(h1.w * c1.w);
                af[tm][ks] = a;
            }

#pragma unroll
        for (int i = 0; i < 8; ++i) {
            const int tnG = w * 8 + i;
            bf16x8 bf[2];
#pragma unroll
            for (int ks = 0; ks < 2; ++ks) {
                const float* wp = W + (size_t)(ks * 32 + kq * 8) * 512 + tnG * 16 + mq;
                bf16x8 b;
#pragma unroll
                for (int j = 0; j < 8; ++j)
                    b[j] = (__bf16)wp[j * 512];   // B[k=r][n=h'] = W[r][h'], strided
                bf[ks] = b;
            }
#pragma unroll
            for (int tm = 0; tm < 2; ++tm) {
                f32x4 acc = {0.f, 0.f, 0.f, 0.f};
                acc = __builtin_amdgcn_mfma_f32_16x16x32_bf16(af[tm][0], bf[0], acc, 0, 0, 0);
                acc = __builtin_amdgcn_mfma_f32_16x16x32_bf16(af[tm][1], bf[1], acc, 0, 0, 0);
                // D: col = mq -> h' = tnG*16+mq; row = kq*4+r -> h-rel = tm*16+kq*4+r
                __bf16* dp = &KTloc[(tm * 16 + kq * 4) * KPAD + tnG * 16 + mq];
#pragma unroll
                for (int r = 0; r < 4; ++r)
                    dp[r * KPAD] = (__bf16)acc[r];
            }
        }
    }
    __syncthreads();

    // ---------------- main loop: out[m0..+16][n0..+32] = hs . KTloc^T ----------------
    const float*  aRow = hs + (size_t)(m0 + mq) * 512 + kq * 8;   // fp32 A
    const __bf16* bR0  = &KTloc[(0  + mq) * KPAD + kq * 8];
    const __bf16* bR1  = &KTloc[(16 + mq) * KPAD + kq * 8];

    f32x4 acc0 = {0.f, 0.f, 0.f, 0.f};
    f32x4 acc1 = {0.f, 0.f, 0.f, 0.f};
#pragma unroll 4
    for (int ks = 0; ks < 16; ++ks) {
        const float4 f0 = *(const float4*)(aRow + ks * 32);
        const float4 f1 = *(const float4*)(aRow + ks * 32 + 4);
        const bf16x8 b0 = *(const bf16x8*)(bR0 + ks * 32);
        const bf16x8 b1 = *(const bf16x8*)(bR1 + ks * 32);
        bf16x8 a;
        a[0] = (__bf16)f0.x; a[1] = (__bf16)f0.y; a[2] = (__bf16)f0.z; a[3] = (__bf16)f0.w;
        a[4] = (__bf16)f1.x; a[5] = (__bf16)f1.y; a[6] = (__bf16)f1.z; a[7] = (__bf16)f1.w;
        acc0 = __builtin_amdgcn_mfma_f32_16x16x32_bf16(a, b0, acc0, 0, 0, 0);
        acc1 = __builtin_amdgcn_mfma_f32_16x16x32_bf16(a, b1, acc1, 0, 0, 0);
    }

    // D: col = mq -> n0+mq (+16); row = kq*4+i -> m0+kq*4+i
    float* op0 = out + (size_t)(m0 + kq * 4) * 512 + n0 + mq;
    float* op1 = op0 + 16;
#pragma unroll
    for (int i = 0; i < 4; ++i) {
        op0[i * 512] = acc0[i];
        op1[i * 512] = acc1[i];
    }
}

extern "C" void kernel_launch(void* const* d_in, const int* in_sizes, int n_in,
                              void* d_out, int out_size, void* d_ws, size_t ws_size,
                              hipStream_t stream) {
    const float* hs = (const float*)d_in[0];  // hidden_states (2,1024,512) f32
    // d_in[1] = all_indices -- identity mapping, unused
    const float* W  = (const float*)d_in[2];  // W_seq (64,512) f32
    const float* he = (const float*)d_in[3];  // hidden_embeddings (512,64) f32
    const float* cp = (const float*)d_in[4];  // cp_weight (1,64) f32
    float* out = (float*)d_out;               // (2,1024,512) f32

    cp_fused_v7<<<dim3(512), dim3(256), 0, stream>>>(hs, W, he, cp, out);
}